// Round 1
// 431.658 us; speedup vs baseline: 1.0270x; 1.0270x over previous
//
#include <hip/hip_runtime.h>
#include <math.h>

// downprompt: fused elementwise + 7-way cosine-sim + softmax.
// v2: 4 lanes per row, 16 rows per wave (was: 64 lanes/row).
//  - butterfly reduction: 2 rounds instead of 6, and each shuffle instr
//    reduces 16 rows at once (48 DS/row -> 2 DS/row)
//  - softmax epilogue redundancy x64 -> x4
//  - coef + ave staged in LDS, read as broadcast ds_read_b128
// Loads stay fully coalesced: each 4-lane group reads contiguous 64B.

__device__ __forceinline__ float elu1(float x) {
    return x > 0.0f ? x : __expf(x) - 1.0f;
}

__device__ __forceinline__ float wave_sum(float v) {
#pragma unroll
    for (int off = 32; off > 0; off >>= 1)
        v += __shfl_xor(v, off, 64);
    return v;
}

__global__ __launch_bounds__(256) void downprompt_kernel(
    const float* __restrict__ seq,
    const float* __restrict__ seq1,
    const float* __restrict__ prompt,
    const float* __restrict__ w_np,
    const float* __restrict__ w_ds,
    const float* __restrict__ w_df,
    const float* __restrict__ ave,
    float* __restrict__ out,
    int N)
{
    __shared__ float s_coef[256];
    __shared__ float s_ave[7][256];

    const int tid  = threadIdx.x;
    const int lane = tid & 63;

    // ---- block setup: stage coef[d] and ave into LDS ----
    {
        const float a  = w_df[0];
        const float b  = w_df[1];
        const float w0 = w_np[0], w1 = w_np[1], w2 = w_np[2];
        const float pr = w0 * prompt[tid] + w1 * prompt[256 + tid]
                       + w2 * prompt[512 + tid];
        // coef[d] = a*(1+elu((w_np@prompt)[d])) + b*w_ds[d]
        s_coef[tid] = a * (1.0f + elu1(pr)) + b * w_ds[tid];
#pragma unroll
        for (int c = 0; c < 7; ++c)
            s_ave[c][tid] = ave[c * 256 + tid];
    }
    __syncthreads();

    // ---- per-wave: prototype norms (redundant per wave, once) ----
    float na[7];
#pragma unroll
    for (int c = 0; c < 7; ++c) {
        const float4 v = *(const float4*)&s_ave[c][lane << 2];
        na[c] = sqrtf(wave_sum(v.x * v.x + v.y * v.y + v.z * v.z + v.w * v.w));
    }

    // ---- 4 lanes per row, 16 rows per wave ----
    const int q   = lane & 3;    // column phase (0..3)
    const int sub = lane >> 2;   // row within group (0..15)
    const int wavesPerBlock = blockDim.x >> 6;
    const int gwave = blockIdx.x * wavesPerBlock + (tid >> 6);
    const int nwave = gridDim.x * wavesPerBlock;
    const int ngroups = (N + 15) >> 4;

    for (int g = gwave; g < ngroups; g += nwave) {
        const int row = (g << 4) + sub;
        if (row >= N) continue;   // quad-uniform: shuffles stay safe

        const float* ps = seq  + (size_t)row * 256;
        const float* pt = seq1 + (size_t)row * 256;

        float acc[8];
#pragma unroll
        for (int k = 0; k < 8; ++k) acc[k] = 0.0f;

#pragma unroll 4
        for (int i = 0; i < 16; ++i) {
            const int col = (i << 4) + (q << 2);
            const float4 s  = *(const float4*)(ps + col);
            const float4 t  = *(const float4*)(pt + col);
            const float4 cf = *(const float4*)&s_coef[col];

            const float r0 = elu1(cf.x * s.x) + 0.1f * t.x;
            const float r1 = elu1(cf.y * s.y) + 0.1f * t.y;
            const float r2 = elu1(cf.z * s.z) + 0.1f * t.z;
            const float r3 = elu1(cf.w * s.w) + 0.1f * t.w;

            acc[7] += r0 * r0 + r1 * r1 + r2 * r2 + r3 * r3;
#pragma unroll
            for (int c = 0; c < 7; ++c) {
                const float4 av = *(const float4*)&s_ave[c][col];
                acc[c] += r0 * av.x + r1 * av.y + r2 * av.z + r3 * av.w;
            }
        }

        // reduce the 8 partials across the 4 lanes of this row's group
#pragma unroll
        for (int off = 1; off <= 2; off <<= 1) {
#pragma unroll
            for (int k = 0; k < 8; ++k)
                acc[k] += __shfl_xor(acc[k], off, 64);
        }

        // softmax over cosine sims (redundant x4 within the group)
        const float nr = sqrtf(acc[7]);
        float sims[7];
        float m = -INFINITY;
#pragma unroll
        for (int c = 0; c < 7; ++c) {
            const float den = fmaxf(nr * na[c], 1e-8f);
            sims[c] = acc[c] * __builtin_amdgcn_rcpf(den);
            m = fmaxf(m, sims[c]);
        }
        float e[7], sum = 0.0f;
#pragma unroll
        for (int c = 0; c < 7; ++c) {
            e[c] = __expf(sims[c] - m);
            sum += e[c];
        }
        const float inv = __builtin_amdgcn_rcpf(sum);

        // lane q writes c=q, and c=q+4 for q<3 (static indices only)
        const float eq  = (q == 0) ? e[0] : (q == 1) ? e[1]
                        : (q == 2) ? e[2] : e[3];
        const float eq4 = (q == 0) ? e[4] : (q == 1) ? e[5] : e[6];

        float* po = out + (size_t)row * 7;
        po[q] = eq * inv;
        if (q < 3) po[q + 4] = eq4 * inv;
    }
}

extern "C" void kernel_launch(void* const* d_in, const int* in_sizes, int n_in,
                              void* d_out, int out_size, void* d_ws, size_t ws_size,
                              hipStream_t stream) {
    const float* seq    = (const float*)d_in[0];
    const float* seq1   = (const float*)d_in[1];
    const float* prompt = (const float*)d_in[2];
    const float* w_np   = (const float*)d_in[3];
    const float* w_ds   = (const float*)d_in[4];
    const float* w_df   = (const float*)d_in[5];
    const float* ave    = (const float*)d_in[6];
    float* out = (float*)d_out;

    const int N = in_sizes[0] / 256;          // 200000
    const int ngroups = (N + 15) / 16;        // 12500 row-groups of 16
    const int wavesPerBlock = 4;
    // target ~2 groups per wave for near-perfect load balance:
    // 1563 blocks * 4 waves = 6252 waves -> 6248 do 2 groups, 4 do 1.
    int blocks = (ngroups + wavesPerBlock * 2 - 1) / (wavesPerBlock * 2);
    if (blocks < 1) blocks = 1;

    downprompt_kernel<<<blocks, 256, 0, stream>>>(seq, seq1, prompt, w_np, w_ds,
                                                  w_df, ave, out, N);
}

// Round 2
// 415.606 us; speedup vs baseline: 1.0666x; 1.0386x over previous
//
#include <hip/hip_runtime.h>
#include <math.h>

// downprompt: fused elementwise + 7-way cosine-sim + softmax.
// v3: attack memory-latency starvation (v2: VALUBusy 17%, HBM 16%, occ 28%).
//  - depth-4 software-pipelined prefetch of seq/seq1 (8 independent 1KB
//    wave-loads in flight per wave instead of 2)
//  - 3125 blocks (12500 waves, one 16-row group per wave) instead of 1563,
//    so CUs stay saturated via block backfill
// Structure otherwise = v2: 4 lanes/row x 16 rows/wave, coef+ave in LDS
// (broadcast ds_read_b128, conflict-free), 2-round quad reduction.

__device__ __forceinline__ float elu1(float x) {
    return x > 0.0f ? x : __expf(x) - 1.0f;
}

__device__ __forceinline__ float wave_sum(float v) {
#pragma unroll
    for (int off = 32; off > 0; off >>= 1)
        v += __shfl_xor(v, off, 64);
    return v;
}

__global__ __launch_bounds__(256) void downprompt_kernel(
    const float* __restrict__ seq,
    const float* __restrict__ seq1,
    const float* __restrict__ prompt,
    const float* __restrict__ w_np,
    const float* __restrict__ w_ds,
    const float* __restrict__ w_df,
    const float* __restrict__ ave,
    float* __restrict__ out,
    int N)
{
    __shared__ float s_coef[256];
    __shared__ float s_ave[7][256];

    const int tid  = threadIdx.x;
    const int lane = tid & 63;

    // ---- block setup: stage coef[d] and ave into LDS ----
    {
        const float a  = w_df[0];
        const float b  = w_df[1];
        const float w0 = w_np[0], w1 = w_np[1], w2 = w_np[2];
        const float pr = w0 * prompt[tid] + w1 * prompt[256 + tid]
                       + w2 * prompt[512 + tid];
        s_coef[tid] = a * (1.0f + elu1(pr)) + b * w_ds[tid];
#pragma unroll
        for (int c = 0; c < 7; ++c)
            s_ave[c][tid] = ave[c * 256 + tid];
    }
    __syncthreads();

    // ---- per-wave: prototype norms (once per wave) ----
    float na[7];
#pragma unroll
    for (int c = 0; c < 7; ++c) {
        const float4 v = *(const float4*)&s_ave[c][lane << 2];
        na[c] = sqrtf(wave_sum(v.x * v.x + v.y * v.y + v.z * v.z + v.w * v.w));
    }

    // ---- 4 lanes per row, 16 rows per wave ----
    const int q   = lane & 3;    // column phase (0..3)
    const int sub = lane >> 2;   // row within group (0..15)
    const int wavesPerBlock = blockDim.x >> 6;
    const int gwave = blockIdx.x * wavesPerBlock + (tid >> 6);
    const int nwave = gridDim.x * wavesPerBlock;
    const int ngroups = (N + 15) >> 4;

    for (int g = gwave; g < ngroups; g += nwave) {
        const int row = (g << 4) + sub;
        if (row >= N) continue;   // quad-uniform: shuffles stay safe

        const float* ps = seq  + (size_t)row * 256 + (q << 2);
        const float* pt = seq1 + (size_t)row * 256 + (q << 2);

        // depth-4 rotating prefetch buffers (fully unrolled -> static idx)
        float4 sb[4], tb[4];
#pragma unroll
        for (int i = 0; i < 4; ++i) {
            sb[i] = *(const float4*)(ps + (i << 4));
            tb[i] = *(const float4*)(pt + (i << 4));
        }

        float acc[8];
#pragma unroll
        for (int k = 0; k < 8; ++k) acc[k] = 0.0f;

#pragma unroll
        for (int i = 0; i < 16; ++i) {
            const float4 s = sb[i & 3];
            const float4 t = tb[i & 3];
            if (i + 4 < 16) {   // static after unroll
                sb[i & 3] = *(const float4*)(ps + ((i + 4) << 4));
                tb[i & 3] = *(const float4*)(pt + ((i + 4) << 4));
            }

            const int col = (i << 4) + (q << 2);
            const float4 cf = *(const float4*)&s_coef[col];

            const float r0 = elu1(cf.x * s.x) + 0.1f * t.x;
            const float r1 = elu1(cf.y * s.y) + 0.1f * t.y;
            const float r2 = elu1(cf.z * s.z) + 0.1f * t.z;
            const float r3 = elu1(cf.w * s.w) + 0.1f * t.w;

            acc[7] += r0 * r0 + r1 * r1 + r2 * r2 + r3 * r3;
#pragma unroll
            for (int c = 0; c < 7; ++c) {
                const float4 av = *(const float4*)&s_ave[c][col];
                acc[c] += r0 * av.x + r1 * av.y + r2 * av.z + r3 * av.w;
            }
        }

        // reduce the 8 partials across the 4 lanes of this row's group
#pragma unroll
        for (int off = 1; off <= 2; off <<= 1) {
#pragma unroll
            for (int k = 0; k < 8; ++k)
                acc[k] += __shfl_xor(acc[k], off, 64);
        }

        // softmax over cosine sims (redundant x4 within the group)
        const float nr = sqrtf(acc[7]);
        float sims[7];
        float m = -INFINITY;
#pragma unroll
        for (int c = 0; c < 7; ++c) {
            const float den = fmaxf(nr * na[c], 1e-8f);
            sims[c] = acc[c] * __builtin_amdgcn_rcpf(den);
            m = fmaxf(m, sims[c]);
        }
        float e[7], sum = 0.0f;
#pragma unroll
        for (int c = 0; c < 7; ++c) {
            e[c] = __expf(sims[c] - m);
            sum += e[c];
        }
        const float inv = __builtin_amdgcn_rcpf(sum);

        // lane q writes c=q, and c=q+4 for q<3 (static indices only)
        const float eq  = (q == 0) ? e[0] : (q == 1) ? e[1]
                        : (q == 2) ? e[2] : e[3];
        const float eq4 = (q == 0) ? e[4] : (q == 1) ? e[5] : e[6];

        float* po = out + (size_t)row * 7;
        po[q] = eq * inv;
        if (q < 3) po[q + 4] = eq4 * inv;
    }
}

extern "C" void kernel_launch(void* const* d_in, const int* in_sizes, int n_in,
                              void* d_out, int out_size, void* d_ws, size_t ws_size,
                              hipStream_t stream) {
    const float* seq    = (const float*)d_in[0];
    const float* seq1   = (const float*)d_in[1];
    const float* prompt = (const float*)d_in[2];
    const float* w_np   = (const float*)d_in[3];
    const float* w_ds   = (const float*)d_in[4];
    const float* w_df   = (const float*)d_in[5];
    const float* ave    = (const float*)d_in[6];
    float* out = (float*)d_out;

    const int N = in_sizes[0] / 256;          // 200000
    const int ngroups = (N + 15) / 16;        // 12500 row-groups of 16
    const int wavesPerBlock = 4;
    // one group per wave: 3125 blocks = 12500 waves; block backfill keeps
    // every CU at max residency for ~2.4 generations (was: 24 waves/CU cap)
    int blocks = (ngroups + wavesPerBlock - 1) / wavesPerBlock;
    if (blocks < 1) blocks = 1;

    downprompt_kernel<<<blocks, 256, 0, stream>>>(seq, seq1, prompt, w_np, w_ds,
                                                  w_df, ave, out, N);
}